// Round 5
// baseline (273.539 us; speedup 1.0000x reference)
//
#include <hip/hip_runtime.h>
#include <cstdint>
#include <cstddef>

// ---------------------------------------------------------------------------
// logsumexp_m[ -0.5*||(s_n - x_m)/std||^2 ] + logc - log M   (N=8192,M=4096,D=784)
// R5: LDS-traffic-bound fix — 256x256 macro-tile, 128x128 output per wave
// (halves LDS bytes per output element), single 64KB buffer with intra-iter
// pipeline: vmcnt(0)/barrier -> ds_read frags -> lgkmcnt(0)/barrier -> issue
// next gld16 -> 64 MFMAs (HBM latency of next tile hides under MFMA burst).
// 32B-quarter XOR swizzle q = g ^ (row&3). fp8 MX K=128 MFMA, norms deferred.
// ---------------------------------------------------------------------------

#define N_ROWS 8192
#define M_ROWS 4096
#define D_DIM  784
#define KPB    896        // K bytes per row (fp8), padded 784 -> 7*128
#define LOG2PI 1.8378770664093453f
#define LOGM   8.317766166719343f   // log(4096)

typedef unsigned char u8;
typedef __attribute__((ext_vector_type(8))) int   i32x8;
typedef __attribute__((ext_vector_type(4))) float f32x4;

__device__ __forceinline__ void gld16(const u8* g, u8* l) {
    __builtin_amdgcn_global_load_lds(
        (__attribute__((address_space(1))) void*)(void*)g,
        (__attribute__((address_space(3))) void*)l, 16, 0, 0);
}

// ------------- k_prep: scale, fp8-round, row norms (wave x 2 rows) ---------
__global__ __launch_bounds__(256) void k_prep(const float* __restrict__ samples,
                                              const float* __restrict__ x,
                                              const float* __restrict__ stdv,
                                              u8* __restrict__ dst,
                                              float* __restrict__ norm) {
    const int wid = threadIdx.x >> 6, lane = threadIdx.x & 63;
    const int row0 = blockIdx.x * 8 + wid * 2;

    float4 rstd[4];
#pragma unroll
    for (int i = 0; i < 4; ++i) {
        int c = lane + 64 * i;
        rstd[i] = make_float4(1.f, 1.f, 1.f, 1.f);
        if (c < 196) {
            float4 d = ((const float4*)stdv)[c];
            rstd[i] = make_float4(1.f / d.x, 1.f / d.y, 1.f / d.z, 1.f / d.w);
        }
    }

#pragma unroll
    for (int rr = 0; rr < 2; ++rr) {
        const int row = row0 + rr;
        const float* src = (row < N_ROWS) ? samples + (size_t)row * D_DIM
                                          : x + (size_t)(row - N_ROWS) * D_DIM;
        unsigned* drow = (unsigned*)(dst + (size_t)row * KPB);
        float sq = 0.f;
#pragma unroll
        for (int i = 0; i < 4; ++i) {
            const int c = lane + 64 * i;       // u32 chunk (4 fp8)
            if (c < 224) {                     // 224*4 = 896 = KPB
                unsigned p = 0;
                if (c < 196) {                 // 196*4 = 784 = D
                    float4 s = ((const float4*)src)[c];
                    float ux = s.x * rstd[i].x, uy = s.y * rstd[i].y;
                    float uz = s.z * rstd[i].z, uw = s.w * rstd[i].w;
                    p = __builtin_amdgcn_cvt_pk_fp8_f32(ux, uy, 0, false);
                    p = __builtin_amdgcn_cvt_pk_fp8_f32(uz, uw, p, true);
                    float r0 = __builtin_amdgcn_cvt_f32_fp8(p, 0);
                    float r1 = __builtin_amdgcn_cvt_f32_fp8(p, 1);
                    float r2 = __builtin_amdgcn_cvt_f32_fp8(p, 2);
                    float r3 = __builtin_amdgcn_cvt_f32_fp8(p, 3);
                    sq += r0 * r0 + r1 * r1 + r2 * r2 + r3 * r3;  // norm of ROUNDED
                }
                drow[c] = p;
            }
        }
        for (int m = 32; m; m >>= 1) sq += __shfl_xor(sq, m);
        if (lane == 0) norm[row] = sq;
    }
}

// -------- k_gemm: 256x256 block tile, 128x128 per wave, fp8 MX K=128 -------
// LDS: A-tile 256 rows x 128 B at [0, 32768), B-tile at [32768, 65536).
// Row r's 32B quarter qg is stored at quarter slot qg ^ (r&3) (16B sub-order
// preserved). Staging permutes the SOURCE granule per lane: dest slot16
// d = lane&7 holds global granule d ^ (2*(r&3)); 8-lane groups still fetch
// one contiguous 128 B global segment. Read: lane (g,rl) wants quarter g of
// row (.. + rl) -> reads quarter slot g ^ (rl&3) as two adjacent b128s.
__global__ __launch_bounds__(256, 1) void k_gemm(const u8* __restrict__ U,
                                                 const u8* __restrict__ V,
                                                 const float* __restrict__ vnorm,
                                                 float* __restrict__ pmax,
                                                 float* __restrict__ psum) {
    __shared__ __align__(16) char smem[65536];

    const int tid = threadIdx.x;
    const int lane = tid & 63;
    const int wid = tid >> 6;
    const int wRow = wid >> 1;          // 128-row half of the 256-row tile
    const int wCol = wid & 1;           // 128-col half
    const int bCol = blockIdx.x;        // 0..15  (M/256)
    const int bRow = blockIdx.y;        // 0..31  (N/256)
    const int g = lane >> 4, rl = lane & 15;

    // ---- staging: wave wid stages A rows [wid*64, +64) and B rows same.
    // 8 chunks each (chunk = 8 rows x 128 B = 1024 B = one gld16).
    const int sr = lane >> 3;                 // row within chunk (0..7)
    const int gc16 = (lane & 7) ^ (2 * (sr & 3));   // swizzled source granule
    const u8* gaB = U + (size_t)(bRow * 256 + wid * 64 + sr) * KPB + gc16 * 16;
    const u8* gbB = V + (size_t)(bCol * 256 + wid * 64 + sr) * KPB + gc16 * 16;
    u8* laB = (u8*)(smem + wid * 8192);       // wave-uniform LDS base (A)
    u8* lbB = (u8*)(smem + 32768 + wid * 8192);

    // ---- frag-read offsets: quarter slot q = g ^ (rl&3)
    const int q = g ^ (rl & 3);
    const int aoff = rl * 128 + q * 32;                   // + i*2048
    const char* aB = smem + wRow * 16384;
    const char* bB = smem + 32768 + wCol * 16384;

    f32x4 acc[8][8];
#pragma unroll
    for (int i = 0; i < 8; ++i)
#pragma unroll
        for (int j = 0; j < 8; ++j) acc[i][j] = (f32x4){0.f, 0.f, 0.f, 0.f};

    // prologue: stage kt=0
#pragma unroll
    for (int t = 0; t < 8; ++t) gld16(gaB + (size_t)t * 8 * KPB, laB + t * 1024);
#pragma unroll
    for (int t = 0; t < 8; ++t) gld16(gbB + (size_t)t * 8 * KPB, lbB + t * 1024);

#pragma unroll
    for (int kt = 0; kt < 7; ++kt) {
        __builtin_amdgcn_s_waitcnt(0x0F70);   // vmcnt(0): tile landed
        __builtin_amdgcn_s_barrier();         // all waves' stores visible

        i32x8 a[8], b[8];
#pragma unroll
        for (int i = 0; i < 8; ++i) {
            int4 L = *(const int4*)(aB + aoff + i * 2048);
            int4 H = *(const int4*)(aB + aoff + i * 2048 + 16);
            a[i] = (i32x8){L.x, L.y, L.z, L.w, H.x, H.y, H.z, H.w};
        }
#pragma unroll
        for (int j = 0; j < 8; ++j) {
            int4 L = *(const int4*)(bB + aoff + j * 2048);
            int4 H = *(const int4*)(bB + aoff + j * 2048 + 16);
            b[j] = (i32x8){L.x, L.y, L.z, L.w, H.x, H.y, H.z, H.w};
        }
        __builtin_amdgcn_s_waitcnt(0xC07F);   // lgkmcnt(0): all frag reads done
        __builtin_amdgcn_s_barrier();         // safe to overwrite buffer

        if (kt < 6) {                         // issue next tile now; HBM latency
            const int k1 = (kt + 1) * 128;    // hides under the MFMA burst below
#pragma unroll
            for (int t = 0; t < 8; ++t) gld16(gaB + (size_t)t * 8 * KPB + k1, laB + t * 1024);
#pragma unroll
            for (int t = 0; t < 8; ++t) gld16(gbB + (size_t)t * 8 * KPB + k1, lbB + t * 1024);
        }

#pragma unroll
        for (int i = 0; i < 8; ++i)
#pragma unroll
            for (int j = 0; j < 8; ++j)
                acc[i][j] = __builtin_amdgcn_mfma_scale_f32_16x16x128_f8f6f4(
                    a[i], b[j], acc[i][j], 0 /*fp8*/, 0 /*fp8*/,
                    0, 127 /*scaleA=1*/, 0, 127 /*scaleB=1*/);
    }

    // ---- epilogue: w = dot - 0.5*vn; per-row LSE partial via 16-lane shuffles.
    // C/D layout: col = rl, row-in-16 = g*4 + reg  (shape-determined)
    float vn[8];
#pragma unroll
    for (int j = 0; j < 8; ++j) vn[j] = vnorm[bCol * 256 + wCol * 128 + j * 16 + rl];

#pragma unroll
    for (int i = 0; i < 8; ++i) {
#pragma unroll
        for (int r = 0; r < 4; ++r) {
            float w[8];
#pragma unroll
            for (int j = 0; j < 8; ++j) w[j] = acc[i][j][r] - 0.5f * vn[j];
            float m = w[0];
#pragma unroll
            for (int j = 1; j < 8; ++j) m = fmaxf(m, w[j]);
#pragma unroll
            for (int msk = 1; msk < 16; msk <<= 1) m = fmaxf(m, __shfl_xor(m, msk));
            float s = 0.f;
#pragma unroll
            for (int j = 0; j < 8; ++j) s += __expf(w[j] - m);
#pragma unroll
            for (int msk = 1; msk < 16; msk <<= 1) s += __shfl_xor(s, msk);
            if (rl == 0) {
                size_t grow = (size_t)(bRow * 256 + wRow * 128 + i * 16 + g * 4 + r);
                pmax[grow * 32 + bCol * 2 + wCol] = m;
                psum[grow * 32 + bCol * 2 + wCol] = s;
            }
        }
    }
}

// --------------- k_final: combine 32 partials + row constants --------------
__global__ __launch_bounds__(256) void k_final(const float* __restrict__ pmax,
                                               const float* __restrict__ psum,
                                               const float* __restrict__ norm,
                                               const float* __restrict__ stdv,
                                               float* __restrict__ out) {
    __shared__ float wsum[4];
    const int t = threadIdx.x;
    float ls = 0.f;
    for (int d = t; d < D_DIM; d += 256) ls += logf(stdv[d]);
    for (int m = 32; m; m >>= 1) ls += __shfl_xor(ls, m);
    if ((t & 63) == 0) wsum[t >> 6] = ls;
    __syncthreads();
    const float logc = -0.5f * (float)D_DIM * LOG2PI - (wsum[0] + wsum[1] + wsum[2] + wsum[3]);

    const int n = blockIdx.x * 256 + t;
    const float* pm = pmax + (size_t)n * 32;
    const float* ps = psum + (size_t)n * 32;
    float gm = pm[0];
#pragma unroll
    for (int c = 1; c < 32; ++c) gm = fmaxf(gm, pm[c]);
    float S = 0.f;
#pragma unroll
    for (int c = 0; c < 32; ++c) S += ps[c] * __expf(pm[c] - gm);
    out[n] = gm + logf(S) - 0.5f * norm[n] + logc - LOGM;
}

// ---------------------------------------------------------------------------
extern "C" void kernel_launch(void* const* d_in, const int* in_sizes, int n_in,
                              void* d_out, int out_size, void* d_ws, size_t ws_size,
                              hipStream_t stream) {
    const float* samples = (const float*)d_in[0];  // 8192*784
    const float* x       = (const float*)d_in[1];  // 4096*784
    const float* stdv    = (const float*)d_in[2];  // 784
    float* out = (float*)d_out;                    // 8192

    char* ws = (char*)d_ws;
    // U fp8 (8192*896) | V fp8 (4096*896) | norm (12288 f32) | pmax | psum
    u8*    U    = (u8*)ws;                        //  7,340,032 B
    u8*    V    = (u8*)(ws + 7340032);            //  3,670,016 B
    float* norm = (float*)(ws + 11010048);        //     49,152 B
    float* pmax = (float*)(ws + 11059200);        //  1,048,576 B
    float* psum = (float*)(ws + 12107776);        //  1,048,576 B  (total ~13.2 MB)

    k_prep<<<(N_ROWS + M_ROWS) / 8, 256, 0, stream>>>(samples, x, stdv, U, norm);
    k_gemm<<<dim3(M_ROWS / 256, N_ROWS / 256), 256, 0, stream>>>(U, V, norm + N_ROWS, pmax, psum);
    k_final<<<N_ROWS / 256, 256, 0, stream>>>(pmax, psum, norm, stdv, out);
}

// Round 6
// 153.750 us; speedup vs baseline: 1.7791x; 1.7791x over previous
//
#include <hip/hip_runtime.h>
#include <cstdint>
#include <cstddef>

// ---------------------------------------------------------------------------
// logsumexp_m[ -0.5*||(s_n - x_m)/std||^2 ] + logc - log M   (N=8192,M=4096,D=784)
// R6: A operands bypass LDS entirely (direct global->VGPR dwordx4 pairs; rows
// are L1/L2-hot across col-blocks) — halves LDS read traffic and conflict
// cycles vs R4. B stays in double-buffered LDS via global_load_lds with R4's
// validated geometry. One __syncthreads per K-iter (double buffer makes the
// second barrier unnecessary). 64x64/wave, fp8 MX K=128, acc ~190 VGPR (no
// spill — R5's 256-reg accumulator spilled to scratch and ran 4.5x slower).
// ---------------------------------------------------------------------------

#define N_ROWS 8192
#define M_ROWS 4096
#define D_DIM  784
#define KPB    896        // K bytes per row (fp8), padded 784 -> 7*128
#define LOG2PI 1.8378770664093453f
#define LOGM   8.317766166719343f   // log(4096)

typedef unsigned char u8;
typedef __attribute__((ext_vector_type(8))) int   i32x8;
typedef __attribute__((ext_vector_type(4))) float f32x4;

__device__ __forceinline__ void gld16(const u8* g, u8* l) {
    __builtin_amdgcn_global_load_lds(
        (__attribute__((address_space(1))) void*)(void*)g,
        (__attribute__((address_space(3))) void*)l, 16, 0, 0);
}

// ------------- k_prep: scale, fp8-round, row norms (1 row/wave) ------------
__global__ __launch_bounds__(256) void k_prep(const float* __restrict__ samples,
                                              const float* __restrict__ x,
                                              const float* __restrict__ stdv,
                                              u8* __restrict__ dst,
                                              float* __restrict__ norm) {
    const int wid = threadIdx.x >> 6, lane = threadIdx.x & 63;
    const int row = blockIdx.x * 4 + wid;
    const float* src = (row < N_ROWS) ? samples + (size_t)row * D_DIM
                                      : x + (size_t)(row - N_ROWS) * D_DIM;
    unsigned* drow = (unsigned*)(dst + (size_t)row * KPB);
    float sq = 0.f;
#pragma unroll
    for (int i = 0; i < 4; ++i) {
        const int c = lane + 64 * i;           // u32 chunk (4 fp8)
        if (c < 224) {                         // 224*4 = 896 = KPB
            unsigned p = 0;
            if (c < 196) {                     // 196*4 = 784 = D
                float4 s = ((const float4*)src)[c];
                float4 d = ((const float4*)stdv)[c];
                float ux = s.x / d.x, uy = s.y / d.y;
                float uz = s.z / d.z, uw = s.w / d.w;
                p = __builtin_amdgcn_cvt_pk_fp8_f32(ux, uy, 0, false);
                p = __builtin_amdgcn_cvt_pk_fp8_f32(uz, uw, p, true);
                float r0 = __builtin_amdgcn_cvt_f32_fp8(p, 0);
                float r1 = __builtin_amdgcn_cvt_f32_fp8(p, 1);
                float r2 = __builtin_amdgcn_cvt_f32_fp8(p, 2);
                float r3 = __builtin_amdgcn_cvt_f32_fp8(p, 3);
                sq += r0 * r0 + r1 * r1 + r2 * r2 + r3 * r3;  // norm of ROUNDED
            }
            drow[c] = p;
        }
    }
    for (int m = 32; m; m >>= 1) sq += __shfl_xor(sq, m);
    if (lane == 0) norm[row] = sq;
}

// ---- k_gemm: 128x128 tile, A in registers, B in double-buffered LDS -------
__global__ __launch_bounds__(256) void k_gemm(const u8* __restrict__ U,
                                              const u8* __restrict__ V,
                                              const float* __restrict__ vnorm,
                                              float* __restrict__ pmax,
                                              float* __restrict__ psum) {
    __shared__ __align__(16) char smem[33792];   // 2 x 16KB B-buffers; epilogue overlay
    float2* part = (float2*)smem;                // [128][33] partials

    const int tid = threadIdx.x;
    const int lane = tid & 63;
    const int wid = tid >> 6;
    const int waveRow = wid >> 1;         // 64-row half
    const int waveCol = wid & 1;          // 64-col half
    const int bCol = blockIdx.x;          // 0..31
    const int bRow = blockIdx.y;          // 0..63
    const int g = lane >> 4, rl = lane & 15;

    // ---- B staging (R4-validated geometry): wave stages 4 chunks/iter.
    // chunk lin = wid*4+t: h = lin&1 (64B K-half), rg = lin>>1 (16 rows x 64B).
    const int r16 = lane >> 2, sl = lane & 3;
    const int gc16 = sl ^ ((r16 >> 1) & 3);          // swizzled source granule
    const u8* gb[4]; int loffB[4];
#pragma unroll
    for (int t = 0; t < 4; ++t) {
        const int lin = wid * 4 + t, h = lin & 1, rg = lin >> 1;
        gb[t] = V + (size_t)(bCol * 128 + rg * 16 + r16) * KPB + h * 64 + gc16 * 16;
        loffB[t] = h * 8192 + rg * 1024;             // wave-uniform LDS offset
    }

    // ---- B frag-read offsets (R4-validated)
    const int key = (rl >> 1) & 3;
    const int hB = (g >> 1) * 8192;
    const int slotLo = (2 * (g & 1)) ^ key;
    const int boff = hB + (waveCol * 64 + rl) * 64 + slotLo * 16;   // + j*1024

    // ---- A direct-load base: lane (g,rl), frag i -> row waveRow*64+i*16+rl,
    // k-bytes [g*32, g*32+32) at kt*128
    const u8* gA = U + (size_t)(bRow * 128 + waveRow * 64 + rl) * KPB + g * 32;

    f32x4 acc[4][4];
#pragma unroll
    for (int i = 0; i < 4; ++i)
#pragma unroll
        for (int j = 0; j < 4; ++j) acc[i][j] = (f32x4){0.f, 0.f, 0.f, 0.f};

    int4 aL[2][4], aH[2][4];

    // prologue: stage kt=0
#pragma unroll
    for (int t = 0; t < 4; ++t) gld16(gb[t], (u8*)(smem + loffB[t]));
#pragma unroll
    for (int i = 0; i < 4; ++i) {
        aL[0][i] = *(const int4*)(gA + (size_t)i * 16 * KPB);
        aH[0][i] = *(const int4*)(gA + (size_t)i * 16 * KPB + 16);
    }

#pragma unroll
    for (int kt = 0; kt < 7; ++kt) {
        const int cur = kt & 1, nxt = cur ^ 1;
        __syncthreads();   // drains vmcnt(0): kt's A+B landed; all waves done
                           // reading buf[nxt] (their kt-1 ds_reads preceded it)
        if (kt < 6) {      // issue kt+1 now; latency hides under ds_read+MFMA
            const int k1 = (kt + 1) * 128;
#pragma unroll
            for (int t = 0; t < 4; ++t)
                gld16(gb[t] + k1, (u8*)(smem + nxt * 16384 + loffB[t]));
#pragma unroll
            for (int i = 0; i < 4; ++i) {
                aL[nxt][i] = *(const int4*)(gA + (size_t)i * 16 * KPB + k1);
                aH[nxt][i] = *(const int4*)(gA + (size_t)i * 16 * KPB + k1 + 16);
            }
        }

        const char* base = smem + cur * 16384;
        i32x8 b[4];
#pragma unroll
        for (int j = 0; j < 4; ++j) {
            int4 L = *(const int4*)(base + (boff + j * 1024));
            int4 H = *(const int4*)(base + ((boff + j * 1024) ^ 16));
            b[j] = (i32x8){L.x, L.y, L.z, L.w, H.x, H.y, H.z, H.w};
        }
#pragma unroll
        for (int i = 0; i < 4; ++i) {
            i32x8 a = (i32x8){aL[cur][i].x, aL[cur][i].y, aL[cur][i].z, aL[cur][i].w,
                              aH[cur][i].x, aH[cur][i].y, aH[cur][i].z, aH[cur][i].w};
#pragma unroll
            for (int j = 0; j < 4; ++j)
                acc[i][j] = __builtin_amdgcn_mfma_scale_f32_16x16x128_f8f6f4(
                    a, b[j], acc[i][j], 0 /*fp8*/, 0 /*fp8*/,
                    0, 127 /*scaleA=1*/, 0, 127 /*scaleB=1*/);
        }
    }
    __syncthreads();   // all LDS reads done before partials overlay

    // ---- epilogue: w = dot - 0.5*vn (un & logc deferred to k_final) ----
    // C/D layout (shape-determined): col = lane&15, row-in-16 = g*4 + reg
    float vn[4];
#pragma unroll
    for (int j = 0; j < 4; ++j) vn[j] = vnorm[bCol * 128 + waveCol * 64 + j * 16 + rl];

    const int prow0 = waveRow * 64 + g * 4;
    const int pcol = waveCol * 16 + rl;
#pragma unroll
    for (int i = 0; i < 4; ++i) {
#pragma unroll
        for (int rg = 0; rg < 4; ++rg) {
            float w0 = acc[i][0][rg] - 0.5f * vn[0];
            float w1 = acc[i][1][rg] - 0.5f * vn[1];
            float w2 = acc[i][2][rg] - 0.5f * vn[2];
            float w3 = acc[i][3][rg] - 0.5f * vn[3];
            float m = fmaxf(fmaxf(w0, w1), fmaxf(w2, w3));
            float s = __expf(w0 - m) + __expf(w1 - m) + __expf(w2 - m) + __expf(w3 - m);
            part[(prow0 + i * 16 + rg) * 33 + pcol] = make_float2(m, s);
        }
    }
    __syncthreads();
    if (tid < 128) {
        const float2* p = part + tid * 33;
        float m = p[0].x;
#pragma unroll
        for (int c = 1; c < 32; ++c) m = fmaxf(m, p[c].x);
        float s = 0.f;
#pragma unroll
        for (int c = 0; c < 32; ++c) { float2 q = p[c]; s += q.y * __expf(q.x - m); }
        size_t grow = (size_t)(bRow * 128 + tid);
        pmax[grow * 32 + bCol] = m;
        psum[grow * 32 + bCol] = s;
    }
}

// --------------- k_final: combine 32 partials + row constants --------------
__global__ __launch_bounds__(256) void k_final(const float* __restrict__ pmax,
                                               const float* __restrict__ psum,
                                               const float* __restrict__ norm,
                                               const float* __restrict__ stdv,
                                               float* __restrict__ out) {
    __shared__ float wsum[4];
    const int t = threadIdx.x;
    float ls = 0.f;
    for (int d = t; d < D_DIM; d += 256) ls += logf(stdv[d]);
    for (int m = 32; m; m >>= 1) ls += __shfl_xor(ls, m);
    if ((t & 63) == 0) wsum[t >> 6] = ls;
    __syncthreads();
    const float logc = -0.5f * (float)D_DIM * LOG2PI - (wsum[0] + wsum[1] + wsum[2] + wsum[3]);

    const int n = blockIdx.x * 256 + t;
    const float* pm = pmax + (size_t)n * 32;
    const float* ps = psum + (size_t)n * 32;
    float gm = pm[0];
#pragma unroll
    for (int c = 1; c < 32; ++c) gm = fmaxf(gm, pm[c]);
    float S = 0.f;
#pragma unroll
    for (int c = 0; c < 32; ++c) S += ps[c] * __expf(pm[c] - gm);
    out[n] = gm + logf(S) - 0.5f * norm[n] + logc - LOGM;
}

// ---------------------------------------------------------------------------
extern "C" void kernel_launch(void* const* d_in, const int* in_sizes, int n_in,
                              void* d_out, int out_size, void* d_ws, size_t ws_size,
                              hipStream_t stream) {
    const float* samples = (const float*)d_in[0];  // 8192*784
    const float* x       = (const float*)d_in[1];  // 4096*784
    const float* stdv    = (const float*)d_in[2];  // 784
    float* out = (float*)d_out;                    // 8192

    char* ws = (char*)d_ws;
    // U fp8 (8192*896) | V fp8 (4096*896) | norm (12288 f32) | pmax | psum
    u8*    U    = (u8*)ws;                        //  7,340,032 B
    u8*    V    = (u8*)(ws + 7340032);            //  3,670,016 B
    float* norm = (float*)(ws + 11010048);        //     49,152 B
    float* pmax = (float*)(ws + 11059200);        //  1,048,576 B
    float* psum = (float*)(ws + 12107776);        //  1,048,576 B  (total ~13.2 MB)

    k_prep<<<(N_ROWS + M_ROWS) / 4, 256, 0, stream>>>(samples, x, stdv, U, norm);
    k_gemm<<<dim3(M_ROWS / 128, N_ROWS / 128), 256, 0, stream>>>(U, V, norm + N_ROWS, pmax, psum);
    k_final<<<N_ROWS / 256, 256, 0, stream>>>(pmax, psum, norm, stdv, out);
}

// Round 7
// 149.662 us; speedup vs baseline: 1.8277x; 1.0273x over previous
//
#include <hip/hip_runtime.h>
#include <cstdint>
#include <cstddef>

// ---------------------------------------------------------------------------
// logsumexp_m[ -0.5*||(s_n - x_m)/std||^2 ] + logc - log M   (N=8192,M=4096,D=784)
// R7: R4 structure (128x128 tile, 64x64/wave, fp8 MX K=128, double-buffered
// LDS, vmcnt(8) pipeline) + NEW fragment-phase-major LDS layout: granule
// (16-row group R, row r, kc16 c) at R*2048 + (c>>2)*1024 + (c&3)*256 + r*16.
// Every ds_read_b128 phase group (16 lanes) reads 256 contiguous aligned
// bytes -> 2 words/bank = conflict-free (m136). Staging permutes lane->global
// granule only (coalescing footprint identical to R4). R6's direct-global A
// reverted (16-line gathers made VMEM the bottleneck).
// ---------------------------------------------------------------------------

#define N_ROWS 8192
#define M_ROWS 4096
#define D_DIM  784
#define KPB    896        // K bytes per row (fp8), padded 784 -> 7*128
#define LOG2PI 1.8378770664093453f
#define LOGM   8.317766166719343f   // log(4096)

typedef unsigned char u8;
typedef __attribute__((ext_vector_type(8))) int   i32x8;
typedef __attribute__((ext_vector_type(4))) float f32x4;

__device__ __forceinline__ void gld16(const u8* g, u8* l) {
    __builtin_amdgcn_global_load_lds(
        (__attribute__((address_space(1))) void*)(void*)g,
        (__attribute__((address_space(3))) void*)l, 16, 0, 0);
}

// ------------- k_prep: scale, fp8-round, row norms (1 row/wave) ------------
__global__ __launch_bounds__(256) void k_prep(const float* __restrict__ samples,
                                              const float* __restrict__ x,
                                              const float* __restrict__ stdv,
                                              u8* __restrict__ dst,
                                              float* __restrict__ norm) {
    const int wid = threadIdx.x >> 6, lane = threadIdx.x & 63;
    const int row = blockIdx.x * 4 + wid;
    const float* src = (row < N_ROWS) ? samples + (size_t)row * D_DIM
                                      : x + (size_t)(row - N_ROWS) * D_DIM;
    unsigned* drow = (unsigned*)(dst + (size_t)row * KPB);
    float sq = 0.f;
#pragma unroll
    for (int i = 0; i < 4; ++i) {
        const int c = lane + 64 * i;           // u32 chunk (4 fp8)
        if (c < 224) {                         // 224*4 = 896 = KPB
            unsigned p = 0;
            if (c < 196) {                     // 196*4 = 784 = D
                float4 s = ((const float4*)src)[c];
                float4 d = ((const float4*)stdv)[c];
                float ux = s.x / d.x, uy = s.y / d.y;
                float uz = s.z / d.z, uw = s.w / d.w;
                p = __builtin_amdgcn_cvt_pk_fp8_f32(ux, uy, 0, false);
                p = __builtin_amdgcn_cvt_pk_fp8_f32(uz, uw, p, true);
                float r0 = __builtin_amdgcn_cvt_f32_fp8(p, 0);
                float r1 = __builtin_amdgcn_cvt_f32_fp8(p, 1);
                float r2 = __builtin_amdgcn_cvt_f32_fp8(p, 2);
                float r3 = __builtin_amdgcn_cvt_f32_fp8(p, 3);
                sq += r0 * r0 + r1 * r1 + r2 * r2 + r3 * r3;  // norm of ROUNDED
            }
            drow[c] = p;
        }
    }
    for (int m = 32; m; m >>= 1) sq += __shfl_xor(sq, m);
    if (lane == 0) norm[row] = sq;
}

// ---------------- k_gemm: 128x128 tile, fp8 MX K=128, pipelined ------------
// LDS buffer (32 KB): A at [0,16384), B at [16384,32768). Within A:
// 16-row group R (0..7), kc16 c (0..7), row r (0..15):
//   addr = R*2048 + (c>>2)*1024 + (c&3)*256 + r*16
// Chunk lin = R*2 + h (h = c>>2) is one gld16 (1 KB): lane l fetches global
// granule (row R*16 + (l&15), byte h*64 + (l>>4)*16) -> lands at slot l. ✓
// Frag read lane (g,rl), frag i: c = 2g (+1): two b128 at
//   (waveRow*4+i)*2048 + (g>>1)*1024 + (g&1)*512 + rl*16   and +256.
// Each 16-lane phase = 256 contiguous aligned bytes -> conflict-free.
__global__ __launch_bounds__(256) void k_gemm(const u8* __restrict__ U,
                                              const u8* __restrict__ V,
                                              const float* __restrict__ vnorm,
                                              float* __restrict__ pmax,
                                              float* __restrict__ psum) {
    __shared__ __align__(16) char smem[65536];
    float2* part = (float2*)smem;          // [128][33] epilogue partials

    const int tid = threadIdx.x;
    const int lane = tid & 63;
    const int wid = tid >> 6;
    const int waveRow = wid >> 1;          // 64-row half
    const int waveCol = wid & 1;           // 64-col half
    const int bCol = blockIdx.x;           // 0..31
    const int bRow = blockIdx.y;           // 0..63
    const int g = lane >> 4, rl = lane & 15;

    // ---- staging: wave stages A chunks {wid*4+t} and B chunks {wid*4+t}.
    // chunk lin: R = lin>>1 (16-row group), h = lin&1 (64B K-half).
    const int srow = lane & 15;                  // row within 16-row group
    const int sc16 = lane >> 4;                  // kc16 within 64B half
    const u8* ga[4]; const u8* gb[4]; int loff[4];
#pragma unroll
    for (int t = 0; t < 4; ++t) {
        const int lin = wid * 4 + t, h = lin & 1, R = lin >> 1;
        ga[t] = U + (size_t)(bRow * 128 + R * 16 + srow) * KPB + h * 64 + sc16 * 16;
        gb[t] = V + (size_t)(bCol * 128 + R * 16 + srow) * KPB + h * 64 + sc16 * 16;
        loff[t] = lin * 1024;                    // wave-uniform LDS offset
    }

    // ---- frag-read offsets (within a buffer): phase-contiguous layout
    const int fo = (g >> 1) * 1024 + (g & 1) * 512 + rl * 16;
    const int aoff = waveRow * 8192 + fo;              // + i*2048, pair at +256
    const int boff = 16384 + waveCol * 8192 + fo;      // + j*2048, pair at +256

    f32x4 acc[4][4];
#pragma unroll
    for (int i = 0; i < 4; ++i)
#pragma unroll
        for (int j = 0; j < 4; ++j) acc[i][j] = (f32x4){0.f, 0.f, 0.f, 0.f};

    // prologue: stage kt=0 into buffer 0
#pragma unroll
    for (int t = 0; t < 4; ++t) gld16(ga[t], (u8*)(smem + loff[t]));
#pragma unroll
    for (int t = 0; t < 4; ++t) gld16(gb[t], (u8*)(smem + 16384 + loff[t]));

#pragma unroll
    for (int kt = 0; kt < 7; ++kt) {
        if (kt < 6) {   // prefetch kt+1 into the other buffer
            char* nb = smem + ((kt + 1) & 1) * 32768;
            const int k1 = (kt + 1) * 128;
#pragma unroll
            for (int t = 0; t < 4; ++t) gld16(ga[t] + k1, (u8*)(nb + loff[t]));
#pragma unroll
            for (int t = 0; t < 4; ++t) gld16(gb[t] + k1, (u8*)(nb + 16384 + loff[t]));
            __builtin_amdgcn_s_waitcnt(0x0F78);   // vmcnt(8): kt landed, kt+1 in flight
        } else {
            __builtin_amdgcn_s_waitcnt(0x0F70);   // vmcnt(0): last tile landed
        }
        __builtin_amdgcn_s_barrier();             // all waves' buf(kt) ready

        const char* base = smem + (kt & 1) * 32768;
        i32x8 a[4], b[4];
#pragma unroll
        for (int i = 0; i < 4; ++i) {
            int4 L = *(const int4*)(base + (aoff + i * 2048));
            int4 H = *(const int4*)(base + (aoff + i * 2048 + 256));
            a[i] = (i32x8){L.x, L.y, L.z, L.w, H.x, H.y, H.z, H.w};
        }
#pragma unroll
        for (int j = 0; j < 4; ++j) {
            int4 L = *(const int4*)(base + (boff + j * 2048));
            int4 H = *(const int4*)(base + (boff + j * 2048 + 256));
            b[j] = (i32x8){L.x, L.y, L.z, L.w, H.x, H.y, H.z, H.w};
        }
#pragma unroll
        for (int i = 0; i < 4; ++i)
#pragma unroll
            for (int j = 0; j < 4; ++j)
                acc[i][j] = __builtin_amdgcn_mfma_scale_f32_16x16x128_f8f6f4(
                    a[i], b[j], acc[i][j], 0 /*fp8*/, 0 /*fp8*/,
                    0, 127 /*scaleA=1*/, 0, 127 /*scaleB=1*/);

        __builtin_amdgcn_s_barrier();             // readers of buf(kt) done
    }
    __syncthreads();   // full drain before partials overlay buffer 0

    // ---- epilogue: w = dot - 0.5*vn (un & logc deferred to k_final) ----
    // C/D layout (shape-determined): col = lane&15, row-in-16 = g*4 + reg
    float vn[4];
#pragma unroll
    for (int j = 0; j < 4; ++j) vn[j] = vnorm[bCol * 128 + waveCol * 64 + j * 16 + rl];

    const int prow0 = waveRow * 64 + g * 4;
    const int pcol = waveCol * 16 + rl;
#pragma unroll
    for (int i = 0; i < 4; ++i) {
#pragma unroll
        for (int rg = 0; rg < 4; ++rg) {
            float w0 = acc[i][0][rg] - 0.5f * vn[0];
            float w1 = acc[i][1][rg] - 0.5f * vn[1];
            float w2 = acc[i][2][rg] - 0.5f * vn[2];
            float w3 = acc[i][3][rg] - 0.5f * vn[3];
            float m = fmaxf(fmaxf(w0, w1), fmaxf(w2, w3));
            float s = __expf(w0 - m) + __expf(w1 - m) + __expf(w2 - m) + __expf(w3 - m);
            part[(prow0 + i * 16 + rg) * 33 + pcol] = make_float2(m, s);
        }
    }
    __syncthreads();
    if (tid < 128) {
        const float2* p = part + tid * 33;
        float m = p[0].x;
#pragma unroll
        for (int c = 1; c < 32; ++c) m = fmaxf(m, p[c].x);
        float s = 0.f;
#pragma unroll
        for (int c = 0; c < 32; ++c) { float2 q = p[c]; s += q.y * __expf(q.x - m); }
        size_t grow = (size_t)(bRow * 128 + tid);
        pmax[grow * 32 + bCol] = m;
        psum[grow * 32 + bCol] = s;
    }
}

// --------------- k_final: combine 32 partials + row constants --------------
__global__ __launch_bounds__(256) void k_final(const float* __restrict__ pmax,
                                               const float* __restrict__ psum,
                                               const float* __restrict__ norm,
                                               const float* __restrict__ stdv,
                                               float* __restrict__ out) {
    __shared__ float wsum[4];
    const int t = threadIdx.x;
    float ls = 0.f;
    for (int d = t; d < D_DIM; d += 256) ls += logf(stdv[d]);
    for (int m = 32; m; m >>= 1) ls += __shfl_xor(ls, m);
    if ((t & 63) == 0) wsum[t >> 6] = ls;
    __syncthreads();
    const float logc = -0.5f * (float)D_DIM * LOG2PI - (wsum[0] + wsum[1] + wsum[2] + wsum[3]);

    const int n = blockIdx.x * 256 + t;
    const float* pm = pmax + (size_t)n * 32;
    const float* ps = psum + (size_t)n * 32;
    float gm = pm[0];
#pragma unroll
    for (int c = 1; c < 32; ++c) gm = fmaxf(gm, pm[c]);
    float S = 0.f;
#pragma unroll
    for (int c = 0; c < 32; ++c) S += ps[c] * __expf(pm[c] - gm);
    out[n] = gm + logf(S) - 0.5f * norm[n] + logc - LOGM;
}

// ---------------------------------------------------------------------------
extern "C" void kernel_launch(void* const* d_in, const int* in_sizes, int n_in,
                              void* d_out, int out_size, void* d_ws, size_t ws_size,
                              hipStream_t stream) {
    const float* samples = (const float*)d_in[0];  // 8192*784
    const float* x       = (const float*)d_in[1];  // 4096*784
    const float* stdv    = (const float*)d_in[2];  // 784
    float* out = (float*)d_out;                    // 8192

    char* ws = (char*)d_ws;
    // U fp8 (8192*896) | V fp8 (4096*896) | norm (12288 f32) | pmax | psum
    u8*    U    = (u8*)ws;                        //  7,340,032 B
    u8*    V    = (u8*)(ws + 7340032);            //  3,670,016 B
    float* norm = (float*)(ws + 11010048);        //     49,152 B
    float* pmax = (float*)(ws + 11059200);        //  1,048,576 B
    float* psum = (float*)(ws + 12107776);        //  1,048,576 B  (total ~13.2 MB)

    k_prep<<<(N_ROWS + M_ROWS) / 4, 256, 0, stream>>>(samples, x, stdv, U, norm);
    k_gemm<<<dim3(M_ROWS / 128, N_ROWS / 128), 256, 0, stream>>>(U, V, norm + N_ROWS, pmax, psum);
    k_final<<<N_ROWS / 256, 256, 0, stream>>>(pmax, psum, norm, stdv, out);
}

// Round 8
// 147.134 us; speedup vs baseline: 1.8591x; 1.0172x over previous
//
#include <hip/hip_runtime.h>
#include <cstdint>
#include <cstddef>

// ---------------------------------------------------------------------------
// logsumexp_m[ -0.5*||(s_n - x_m)/std||^2 ] + logc - log M   (N=8192,M=4096,D=784)
// R8: drop global_load_lds (its lane->slot lock forces EITHER strided global
// (R7, VMEM-bound) OR conflicted reads (R4)). Stage via coalesced
// global_load_dwordx4 -> ds_write_b128 into a rotated row-minor layout:
//   granule (r, c_lo) of chunk (R,h) at R*2048 + h*1024 + c_lo*256
//                                      + ((r + 4*c_lo)&15)*16
// Reads: 16-lane phase = rotated-contiguous 256B block -> 0 conflicts
// (R7-validated). Writes: v=(r+4c_lo)&15 all distinct -> 2 words/bank = free.
// Barriers need only lgkmcnt(0) (no vmcnt drain) -> kt+1 global prefetch
// stays in flight across the barrier. fp8 MX K=128, 64x64/wave, dbuf LDS.
// ---------------------------------------------------------------------------

#define N_ROWS 8192
#define M_ROWS 4096
#define D_DIM  784
#define KPB    896        // K bytes per row (fp8), padded 784 -> 7*128
#define LOG2PI 1.8378770664093453f
#define LOGM   8.317766166719343f   // log(4096)

typedef unsigned char u8;
typedef __attribute__((ext_vector_type(8))) int   i32x8;
typedef __attribute__((ext_vector_type(4))) float f32x4;

// ------------- k_prep: scale, fp8-round, row norms (1 row/wave) ------------
__global__ __launch_bounds__(256) void k_prep(const float* __restrict__ samples,
                                              const float* __restrict__ x,
                                              const float* __restrict__ stdv,
                                              u8* __restrict__ dst,
                                              float* __restrict__ norm) {
    const int wid = threadIdx.x >> 6, lane = threadIdx.x & 63;
    const int row = blockIdx.x * 4 + wid;
    const float* src = (row < N_ROWS) ? samples + (size_t)row * D_DIM
                                      : x + (size_t)(row - N_ROWS) * D_DIM;
    unsigned* drow = (unsigned*)(dst + (size_t)row * KPB);
    float sq = 0.f;
#pragma unroll
    for (int i = 0; i < 4; ++i) {
        const int c = lane + 64 * i;           // u32 chunk (4 fp8)
        if (c < 224) {                         // 224*4 = 896 = KPB
            unsigned p = 0;
            if (c < 196) {                     // 196*4 = 784 = D
                float4 s = ((const float4*)src)[c];
                float4 d = ((const float4*)stdv)[c];
                float ux = s.x / d.x, uy = s.y / d.y;
                float uz = s.z / d.z, uw = s.w / d.w;
                p = __builtin_amdgcn_cvt_pk_fp8_f32(ux, uy, 0, false);
                p = __builtin_amdgcn_cvt_pk_fp8_f32(uz, uw, p, true);
                float r0 = __builtin_amdgcn_cvt_f32_fp8(p, 0);
                float r1 = __builtin_amdgcn_cvt_f32_fp8(p, 1);
                float r2 = __builtin_amdgcn_cvt_f32_fp8(p, 2);
                float r3 = __builtin_amdgcn_cvt_f32_fp8(p, 3);
                sq += r0 * r0 + r1 * r1 + r2 * r2 + r3 * r3;  // norm of ROUNDED
            }
            drow[c] = p;
        }
    }
    for (int m = 32; m; m >>= 1) sq += __shfl_xor(sq, m);
    if (lane == 0) norm[row] = sq;
}

// ---------------- k_gemm: 128x128 tile, fp8 MX K=128, pipelined ------------
__global__ __launch_bounds__(256) void k_gemm(const u8* __restrict__ U,
                                              const u8* __restrict__ V,
                                              const float* __restrict__ vnorm,
                                              float* __restrict__ pmax,
                                              float* __restrict__ psum) {
    __shared__ __align__(16) char smem[65536];   // 2 buffers x (A 16KB | B 16KB)
    float2* part = (float2*)smem;                // [128][33] epilogue partials

    const int tid = threadIdx.x;
    const int lane = tid & 63;
    const int wid = tid >> 6;
    const int waveRow = wid >> 1;          // 64-row half
    const int waveCol = wid & 1;           // 64-col half
    const int bCol = blockIdx.x;           // 0..31
    const int bRow = blockIdx.y;           // 0..63
    const int g = lane >> 4, rl = lane & 15;

    // ---- staging: wave stages A chunks lin=wid*4+t and B chunks same.
    // chunk lin: R = lin>>1 (16-row group), h = lin&1 (64B K-half).
    // lane l: global (row R*16 + (l>>2), byte h*64 + (l&3)*16)  [coalesced:
    // 4 lanes per 64B row segment], LDS slot c_lo=l&3, r=l>>2, rotated.
    const int sr = lane >> 2;              // row within 16-row group
    const int sc = lane & 3;               // c_lo granule
    const int wsub = sc * 256 + (((sr + 4 * sc) & 15) * 16);   // rotated slot
    const u8* ga[4]; const u8* gb[4]; int loff[4];
#pragma unroll
    for (int t = 0; t < 4; ++t) {
        const int lin = wid * 4 + t, h = lin & 1, R = lin >> 1;
        ga[t] = U + (size_t)(bRow * 128 + R * 16 + sr) * KPB + h * 64 + sc * 16;
        gb[t] = V + (size_t)(bCol * 128 + R * 16 + sr) * KPB + h * 64 + sc * 16;
        loff[t] = lin * 1024 + wsub;       // LDS offset within A/B tile
    }

    // ---- frag-read offsets: lane (g,rl) reads granules cL=2(g&1), cH=cL+1
    // of k-half h=g>>1, row rl; rotation depends on c_lo.
    const int h = g >> 1;
    const int cL = 2 * (g & 1), cH = cL + 1;
    const int foL = h * 1024 + cL * 256 + (((rl + 4 * cL) & 15) * 16);
    const int foH = h * 1024 + cH * 256 + (((rl + 4 * cH) & 15) * 16);
    const int aoffL = waveRow * 8192 + foL;            // + i*2048
    const int aoffH = waveRow * 8192 + foH;
    const int boffL = 16384 + waveCol * 8192 + foL;    // + j*2048
    const int boffH = 16384 + waveCol * 8192 + foH;

    f32x4 acc[4][4];
#pragma unroll
    for (int i = 0; i < 4; ++i)
#pragma unroll
        for (int j = 0; j < 4; ++j) acc[i][j] = (f32x4){0.f, 0.f, 0.f, 0.f};

    // prologue: load kt=0 into registers
    int4 ra[4], rb[4];
#pragma unroll
    for (int t = 0; t < 4; ++t) ra[t] = *(const int4*)(ga[t]);
#pragma unroll
    for (int t = 0; t < 4; ++t) rb[t] = *(const int4*)(gb[t]);

#pragma unroll
    for (int kt = 0; kt < 7; ++kt) {
        char* wb = smem + (kt & 1) * 32768;
        // write kt's tile (compiler inserts the exact vmcnt for ra/rb deps)
#pragma unroll
        for (int t = 0; t < 4; ++t) *(int4*)(wb + loff[t]) = ra[t];
#pragma unroll
        for (int t = 0; t < 4; ++t) *(int4*)(wb + 16384 + loff[t]) = rb[t];

        if (kt < 6) {   // prefetch kt+1; stays in flight across the barrier
            const int k1 = (kt + 1) * 128;
#pragma unroll
            for (int t = 0; t < 4; ++t) ra[t] = *(const int4*)(ga[t] + k1);
#pragma unroll
            for (int t = 0; t < 4; ++t) rb[t] = *(const int4*)(gb[t] + k1);
        }

        __builtin_amdgcn_s_waitcnt(0xC07F);   // lgkmcnt(0): my LDS writes done
        __builtin_amdgcn_s_barrier();         // all waves' writes visible
                                              // (NO vmcnt drain — prefetch live)
        const char* base = smem + (kt & 1) * 32768;
        i32x8 a[4], b[4];
#pragma unroll
        for (int i = 0; i < 4; ++i) {
            int4 L = *(const int4*)(base + (aoffL + i * 2048));
            int4 H = *(const int4*)(base + (aoffH + i * 2048));
            a[i] = (i32x8){L.x, L.y, L.z, L.w, H.x, H.y, H.z, H.w};
        }
#pragma unroll
        for (int j = 0; j < 4; ++j) {
            int4 L = *(const int4*)(base + (boffL + j * 2048));
            int4 H = *(const int4*)(base + (boffH + j * 2048));
            b[j] = (i32x8){L.x, L.y, L.z, L.w, H.x, H.y, H.z, H.w};
        }
#pragma unroll
        for (int i = 0; i < 4; ++i)
#pragma unroll
            for (int j = 0; j < 4; ++j)
                acc[i][j] = __builtin_amdgcn_mfma_scale_f32_16x16x128_f8f6f4(
                    a[i], b[j], acc[i][j], 0 /*fp8*/, 0 /*fp8*/,
                    0, 127 /*scaleA=1*/, 0, 127 /*scaleB=1*/);
        // next iter's lgkmcnt(0)+barrier protects buf reuse (reads drained
        // before any wave can reach the kt+2 writes to this buffer)
    }
    __syncthreads();   // full drain before partials overlay buffer 0

    // ---- epilogue: w = dot - 0.5*vn (un & logc deferred to k_final) ----
    // C/D layout (shape-determined): col = lane&15, row-in-16 = g*4 + reg
    float vn[4];
#pragma unroll
    for (int j = 0; j < 4; ++j) vn[j] = vnorm[bCol * 128 + waveCol * 64 + j * 16 + rl];

    const int prow0 = waveRow * 64 + g * 4;
    const int pcol = waveCol * 16 + rl;
#pragma unroll
    for (int i = 0; i < 4; ++i) {
#pragma unroll
        for (int rg = 0; rg < 4; ++rg) {
            float w0 = acc[i][0][rg] - 0.5f * vn[0];
            float w1 = acc[i][1][rg] - 0.5f * vn[1];
            float w2 = acc[i][2][rg] - 0.5f * vn[2];
            float w3 = acc[i][3][rg] - 0.5f * vn[3];
            float m = fmaxf(fmaxf(w0, w1), fmaxf(w2, w3));
            float s = __expf(w0 - m) + __expf(w1 - m) + __expf(w2 - m) + __expf(w3 - m);
            part[(prow0 + i * 16 + rg) * 33 + pcol] = make_float2(m, s);
        }
    }
    __syncthreads();
    if (tid < 128) {
        const float2* p = part + tid * 33;
        float m = p[0].x;
#pragma unroll
        for (int c = 1; c < 32; ++c) m = fmaxf(m, p[c].x);
        float s = 0.f;
#pragma unroll
        for (int c = 0; c < 32; ++c) { float2 q = p[c]; s += q.y * __expf(q.x - m); }
        size_t grow = (size_t)(bRow * 128 + tid);
        pmax[grow * 32 + bCol] = m;
        psum[grow * 32 + bCol] = s;
    }
}

// --------------- k_final: combine 32 partials + row constants --------------
__global__ __launch_bounds__(256) void k_final(const float* __restrict__ pmax,
                                               const float* __restrict__ psum,
                                               const float* __restrict__ norm,
                                               const float* __restrict__ stdv,
                                               float* __restrict__ out) {
    __shared__ float wsum[4];
    const int t = threadIdx.x;
    float ls = 0.f;
    for (int d = t; d < D_DIM; d += 256) ls += logf(stdv[d]);
    for (int m = 32; m; m >>= 1) ls += __shfl_xor(ls, m);
    if ((t & 63) == 0) wsum[t >> 6] = ls;
    __syncthreads();
    const float logc = -0.5f * (float)D_DIM * LOG2PI - (wsum[0] + wsum[1] + wsum[2] + wsum[3]);

    const int n = blockIdx.x * 256 + t;
    const float* pm = pmax + (size_t)n * 32;
    const float* ps = psum + (size_t)n * 32;
    float gm = pm[0];
#pragma unroll
    for (int c = 1; c < 32; ++c) gm = fmaxf(gm, pm[c]);
    float S = 0.f;
#pragma unroll
    for (int c = 0; c < 32; ++c) S += ps[c] * __expf(pm[c] - gm);
    out[n] = gm + logf(S) - 0.5f * norm[n] + logc - LOGM;
}

// ---------------------------------------------------------------------------
extern "C" void kernel_launch(void* const* d_in, const int* in_sizes, int n_in,
                              void* d_out, int out_size, void* d_ws, size_t ws_size,
                              hipStream_t stream) {
    const float* samples = (const float*)d_in[0];  // 8192*784
    const float* x       = (const float*)d_in[1];  // 4096*784
    const float* stdv    = (const float*)d_in[2];  // 784
    float* out = (float*)d_out;                    // 8192

    char* ws = (char*)d_ws;
    // U fp8 (8192*896) | V fp8 (4096*896) | norm (12288 f32) | pmax | psum
    u8*    U    = (u8*)ws;                        //  7,340,032 B
    u8*    V    = (u8*)(ws + 7340032);            //  3,670,016 B
    float* norm = (float*)(ws + 11010048);        //     49,152 B
    float* pmax = (float*)(ws + 11059200);        //  1,048,576 B
    float* psum = (float*)(ws + 12107776);        //  1,048,576 B  (total ~13.2 MB)

    k_prep<<<(N_ROWS + M_ROWS) / 4, 256, 0, stream>>>(samples, x, stdv, U, norm);
    k_gemm<<<dim3(M_ROWS / 128, N_ROWS / 128), 256, 0, stream>>>(U, V, norm + N_ROWS, pmax, psum);
    k_final<<<N_ROWS / 256, 256, 0, stream>>>(pmax, psum, norm, stdv, out);
}

// Round 9
// 124.758 us; speedup vs baseline: 2.1926x; 1.1794x over previous
//
#include <hip/hip_runtime.h>
#include <cstdint>
#include <cstddef>

// ---------------------------------------------------------------------------
// logsumexp_m[ -0.5*||(s_n - x_m)/std||^2 ] + logc - log M   (N=8192,M=4096,D=784)
// R9: PRE-SWIZZLED operand panels. k_prep writes U,V into the exact R7 LDS
// image, panel-major:  st[panel=row>>4][kt][h][(sc16*16 + (row&15))*16]
// so k_gemm's global_load_lds chunks are 1KB CONTIGUOUS in global memory
// (perfect coalescing), land at slot=lane (R7 image), and fragment reads are
// the R7 phase-contiguous pattern (measured 0 bank conflicts). This resolves
// the three-way coalesce/write/read conflict that R4/R7/R8 each hit one leg
// of. K-loop keeps R4's validated vmcnt(8) double-buffer pipeline.
// fp8 MX K=128 MFMA, 64x64/wave, norms/constants deferred to k_final.
// ---------------------------------------------------------------------------

#define N_ROWS 8192
#define M_ROWS 4096
#define D_DIM  784
#define KPB    896        // K bytes per row (fp8), padded 784 -> 7*128
#define PANEL  14336      // 16 rows * 896 B, chunk-interleaved
#define LOG2PI 1.8378770664093453f
#define LOGM   8.317766166719343f   // log(4096)

typedef unsigned char u8;
typedef __attribute__((ext_vector_type(8))) int   i32x8;
typedef __attribute__((ext_vector_type(4))) float f32x4;

__device__ __forceinline__ void gld16(const u8* g, u8* l) {
    __builtin_amdgcn_global_load_lds(
        (__attribute__((address_space(1))) void*)(void*)g,
        (__attribute__((address_space(3))) void*)l, 16, 0, 0);
}

// ------------- k_prep: scale, fp8-round, panel-staged store, row norms -----
// one row per wave. Staged address for granule c16 (16B) of row:
//   panel(row>>4)*14336 + (c16>>3)*2048 + ((c16>>2)&1)*1024
//   + ((c16&3)*16 + (row&15))*16
__global__ __launch_bounds__(256) void k_prep(const float* __restrict__ samples,
                                              const float* __restrict__ x,
                                              const float* __restrict__ stdv,
                                              u8* __restrict__ Ust,
                                              u8* __restrict__ Vst,
                                              float* __restrict__ norm) {
    const int wid = threadIdx.x >> 6, lane = threadIdx.x & 63;
    const int row = blockIdx.x * 4 + wid;
    const bool isU = row < N_ROWS;
    const int lrow = isU ? row : row - N_ROWS;
    const float* src = isU ? samples + (size_t)lrow * D_DIM
                           : x + (size_t)lrow * D_DIM;
    u8* st = (isU ? Ust : Vst) + (size_t)(lrow >> 4) * PANEL;
    const int r = lrow & 15;
    float sq = 0.f;
#pragma unroll
    for (int i = 0; i < 4; ++i) {
        const int c = lane + 64 * i;           // u32 chunk (4 fp8)
        if (c < 224) {                         // 224*4 = 896 = KPB
            unsigned p = 0;
            if (c < 196) {                     // 196*4 = 784 = D
                float4 s = ((const float4*)src)[c];
                float4 d = ((const float4*)stdv)[c];
                float ux = s.x / d.x, uy = s.y / d.y;
                float uz = s.z / d.z, uw = s.w / d.w;
                p = __builtin_amdgcn_cvt_pk_fp8_f32(ux, uy, 0, false);
                p = __builtin_amdgcn_cvt_pk_fp8_f32(uz, uw, p, true);
                float r0 = __builtin_amdgcn_cvt_f32_fp8(p, 0);
                float r1 = __builtin_amdgcn_cvt_f32_fp8(p, 1);
                float r2 = __builtin_amdgcn_cvt_f32_fp8(p, 2);
                float r3 = __builtin_amdgcn_cvt_f32_fp8(p, 3);
                sq += r0 * r0 + r1 * r1 + r2 * r2 + r3 * r3;  // norm of ROUNDED
            }
            const int c16 = c >> 2;
            const int off = (c16 >> 3) * 2048 + ((c16 >> 2) & 1) * 1024
                          + ((c16 & 3) * 16 + r) * 16 + (c & 3) * 4;
            *(unsigned*)(st + off) = p;
        }
    }
    for (int m = 32; m; m >>= 1) sq += __shfl_xor(sq, m);
    if (lane == 0) norm[row] = sq;
}

// ---------------- k_gemm: 128x128 tile, fp8 MX K=128, pipelined ------------
// Staging: chunk (R local group, h) at staged ( (bRow*8+R)*PANEL + kt*2048
// + h*1024 ), 1KB contiguous; gld16 lands lane l at slot l*16 -> R7 image:
// within chunk, slot (sc16*16 + r)*16 holds granule (row r, kc16 = h*4+sc16).
// Frag reads (R7, measured 0-conflict): lane (g,rl), frag i:
//   aoff = waveRow*8192 + (g>>1)*1024 + (g&1)*512 + rl*16  (+i*2048, pair +256)
__global__ __launch_bounds__(256) void k_gemm(const u8* __restrict__ U,
                                              const u8* __restrict__ V,
                                              const float* __restrict__ vnorm,
                                              float* __restrict__ pmax,
                                              float* __restrict__ psum) {
    __shared__ __align__(16) char smem[65536];
    float2* part = (float2*)smem;          // [128][33] epilogue partials

    const int tid = threadIdx.x;
    const int lane = tid & 63;
    const int wid = tid >> 6;
    const int waveRow = wid >> 1;          // 64-row half
    const int waveCol = wid & 1;           // 64-col half
    const int bCol = blockIdx.x;           // 0..31
    const int bRow = blockIdx.y;           // 0..63
    const int g = lane >> 4, rl = lane & 15;

    // wave stages A chunks lin=wid*4+t and B chunks same (lin: R=lin>>1, h=lin&1)
    const u8* ga[4]; const u8* gb[4]; int loff[4];
#pragma unroll
    for (int t = 0; t < 4; ++t) {
        const int lin = wid * 4 + t, h = lin & 1, R = lin >> 1;
        ga[t] = U + (size_t)(bRow * 8 + R) * PANEL + h * 1024 + lane * 16;
        gb[t] = V + (size_t)(bCol * 8 + R) * PANEL + h * 1024 + lane * 16;
        loff[t] = lin * 1024;              // wave-uniform LDS offset
    }

    // frag-read offsets (R7-validated, 0 conflicts)
    const int fo = (g >> 1) * 1024 + (g & 1) * 512 + rl * 16;
    const int aoff = waveRow * 8192 + fo;              // + i*2048, pair at +256
    const int boff = 16384 + waveCol * 8192 + fo;      // + j*2048, pair at +256

    f32x4 acc[4][4];
#pragma unroll
    for (int i = 0; i < 4; ++i)
#pragma unroll
        for (int j = 0; j < 4; ++j) acc[i][j] = (f32x4){0.f, 0.f, 0.f, 0.f};

    // prologue: stage kt=0 into buffer 0
#pragma unroll
    for (int t = 0; t < 4; ++t) gld16(ga[t], (u8*)(smem + loff[t]));
#pragma unroll
    for (int t = 0; t < 4; ++t) gld16(gb[t], (u8*)(smem + 16384 + loff[t]));

#pragma unroll
    for (int kt = 0; kt < 7; ++kt) {
        if (kt < 6) {   // prefetch kt+1 into the other buffer
            char* nb = smem + ((kt + 1) & 1) * 32768;
            const int k1 = (kt + 1) * 2048;
#pragma unroll
            for (int t = 0; t < 4; ++t) gld16(ga[t] + k1, (u8*)(nb + loff[t]));
#pragma unroll
            for (int t = 0; t < 4; ++t) gld16(gb[t] + k1, (u8*)(nb + 16384 + loff[t]));
            __builtin_amdgcn_s_waitcnt(0x0F78);   // vmcnt(8): kt landed, kt+1 in flight
        } else {
            __builtin_amdgcn_s_waitcnt(0x0F70);   // vmcnt(0): last tile landed
        }
        __builtin_amdgcn_s_barrier();             // all waves' buf(kt) ready

        const char* base = smem + (kt & 1) * 32768;
        i32x8 a[4], b[4];
#pragma unroll
        for (int i = 0; i < 4; ++i) {
            int4 L = *(const int4*)(base + (aoff + i * 2048));
            int4 H = *(const int4*)(base + (aoff + i * 2048 + 256));
            a[i] = (i32x8){L.x, L.y, L.z, L.w, H.x, H.y, H.z, H.w};
        }
#pragma unroll
        for (int j = 0; j < 4; ++j) {
            int4 L = *(const int4*)(base + (boff + j * 2048));
            int4 H = *(const int4*)(base + (boff + j * 2048 + 256));
            b[j] = (i32x8){L.x, L.y, L.z, L.w, H.x, H.y, H.z, H.w};
        }
#pragma unroll
        for (int i = 0; i < 4; ++i)
#pragma unroll
            for (int j = 0; j < 4; ++j)
                acc[i][j] = __builtin_amdgcn_mfma_scale_f32_16x16x128_f8f6f4(
                    a[i], b[j], acc[i][j], 0 /*fp8*/, 0 /*fp8*/,
                    0, 127 /*scaleA=1*/, 0, 127 /*scaleB=1*/);

        __builtin_amdgcn_s_barrier();             // readers of buf(kt) done
    }
    __syncthreads();   // full drain before partials overlay buffer 0

    // ---- epilogue: w = dot - 0.5*vn (un & logc deferred to k_final) ----
    // C/D layout (shape-determined): col = lane&15, row-in-16 = g*4 + reg
    float vn[4];
#pragma unroll
    for (int j = 0; j < 4; ++j) vn[j] = vnorm[bCol * 128 + waveCol * 64 + j * 16 + rl];

    const int prow0 = waveRow * 64 + g * 4;
    const int pcol = waveCol * 16 + rl;
#pragma unroll
    for (int i = 0; i < 4; ++i) {
#pragma unroll
        for (int rg = 0; rg < 4; ++rg) {
            float w0 = acc[i][0][rg] - 0.5f * vn[0];
            float w1 = acc[i][1][rg] - 0.5f * vn[1];
            float w2 = acc[i][2][rg] - 0.5f * vn[2];
            float w3 = acc[i][3][rg] - 0.5f * vn[3];
            float m = fmaxf(fmaxf(w0, w1), fmaxf(w2, w3));
            float s = __expf(w0 - m) + __expf(w1 - m) + __expf(w2 - m) + __expf(w3 - m);
            part[(prow0 + i * 16 + rg) * 33 + pcol] = make_float2(m, s);
        }
    }
    __syncthreads();
    if (tid < 128) {
        const float2* p = part + tid * 33;
        float m = p[0].x;
#pragma unroll
        for (int c = 1; c < 32; ++c) m = fmaxf(m, p[c].x);
        float s = 0.f;
#pragma unroll
        for (int c = 0; c < 32; ++c) { float2 q = p[c]; s += q.y * __expf(q.x - m); }
        size_t grow = (size_t)(bRow * 128 + tid);
        pmax[grow * 32 + bCol] = m;
        psum[grow * 32 + bCol] = s;
    }
}

// --------------- k_final: combine 32 partials + row constants --------------
__global__ __launch_bounds__(256) void k_final(const float* __restrict__ pmax,
                                               const float* __restrict__ psum,
                                               const float* __restrict__ norm,
                                               const float* __restrict__ stdv,
                                               float* __restrict__ out) {
    __shared__ float wsum[4];
    const int t = threadIdx.x;
    float ls = 0.f;
    for (int d = t; d < D_DIM; d += 256) ls += logf(stdv[d]);
    for (int m = 32; m; m >>= 1) ls += __shfl_xor(ls, m);
    if ((t & 63) == 0) wsum[t >> 6] = ls;
    __syncthreads();
    const float logc = -0.5f * (float)D_DIM * LOG2PI - (wsum[0] + wsum[1] + wsum[2] + wsum[3]);

    const int n = blockIdx.x * 256 + t;
    const float* pm = pmax + (size_t)n * 32;
    const float* ps = psum + (size_t)n * 32;
    float gm = pm[0];
#pragma unroll
    for (int c = 1; c < 32; ++c) gm = fmaxf(gm, pm[c]);
    float S = 0.f;
#pragma unroll
    for (int c = 0; c < 32; ++c) S += ps[c] * __expf(pm[c] - gm);
    out[n] = gm + logf(S) - 0.5f * norm[n] + logc - LOGM;
}

// ---------------------------------------------------------------------------
extern "C" void kernel_launch(void* const* d_in, const int* in_sizes, int n_in,
                              void* d_out, int out_size, void* d_ws, size_t ws_size,
                              hipStream_t stream) {
    const float* samples = (const float*)d_in[0];  // 8192*784
    const float* x       = (const float*)d_in[1];  // 4096*784
    const float* stdv    = (const float*)d_in[2];  // 784
    float* out = (float*)d_out;                    // 8192

    char* ws = (char*)d_ws;
    // U_st (512 panels * 14336) | V_st (256 panels) | norm | pmax | psum
    u8*    U    = (u8*)ws;                        //  7,340,032 B
    u8*    V    = (u8*)(ws + 7340032);            //  3,670,016 B
    float* norm = (float*)(ws + 11010048);        //     49,152 B
    float* pmax = (float*)(ws + 11059200);        //  1,048,576 B
    float* psum = (float*)(ws + 12107776);        //  1,048,576 B  (total ~13.2 MB)

    k_prep<<<(N_ROWS + M_ROWS) / 4, 256, 0, stream>>>(samples, x, stdv, U, V, norm);
    k_gemm<<<dim3(M_ROWS / 128, N_ROWS / 128), 256, 0, stream>>>(U, V, norm + N_ROWS, pmax, psum);
    k_final<<<N_ROWS / 256, 256, 0, stream>>>(pmax, psum, norm, stdv, out);
}